// Round 7
// baseline (488.113 us; speedup 1.0000x reference)
//
#include <hip/hip_runtime.h>
#include <hip/hip_bf16.h>
#include <math.h>

#define C_CH 8
#define H_DIM 512
#define BS 32768            // B*S
#define K_DIM 4096          // C*H
#define EPS 1e-5f

#define TM 64
#define TK 32
#define NKT (K_DIM / TK)    // 128 K-tiles

typedef __bf16 bf16x8 __attribute__((ext_vector_type(8)));
typedef __bf16 bf16x4 __attribute__((ext_vector_type(4)));
typedef float  floatx4 __attribute__((ext_vector_type(4)));

// Dynamic-LDS layout (78 KB > 64 KB static limit):
//   BLS  [2 rings][32 chunks][1 KB]  = 65536   B frag chunks (wave w owns chunks w*4..w*4+3)
//   ALS  [2 rings][4 KB]             = 8192    A frag chunks (chunk mt: lane l -> A[mt*16+(l&15)][(l>>4)*8+i])
//   PS   [8][64] f32                 = 2048
//   QS   [8][64] f32                 = 2048
//   ST   legacy stats                = 256
// Epilogue overlays redS/redQ/muS/invS into BLS (dead after vmcnt(0) drain).
// Legacy path overlays rS at BLS+8192 (legacy never uses BLS).
#define SMEM_BLS 0
#define SMEM_ALS 65536
#define SMEM_PS  73728
#define SMEM_QS  75776
#define SMEM_ST  77824
#define SMEM_SZ  78080

// tanh-form GELU, exp2-folded; max abs dev from exact erf-gelu ~3e-4.
__device__ __forceinline__ float gelu_fast(float v) {
    float x2 = v * fmaf(v * v, 0.102943215f, 2.30220815f);   // x*log2e
    float e = __builtin_amdgcn_exp2f(-x2);
    return v * __builtin_amdgcn_rcpf(1.0f + e);
}

// async global->LDS, 16B per lane; LDS dest = wave-uniform base + lane*16
__device__ __forceinline__ void gld_lds16(const void* g, void* l) {
    __builtin_amdgcn_global_load_lds(
        (const __attribute__((address_space(1))) void*)g,
        (__attribute__((address_space(3))) void*)l, 16, 0, 0);
}

// Prep kernel, grid = 1024 + 8 blocks x 256 threads (unchanged layout).
// Blocks [0,1024): mod_w fp32 [512][4096] -> bf16 workspace in MFMA B-fragment
//   chunk layout: chunk(kt 0..127, ntile 0..31) of 64 lanes x 16B; lane l holds
//   B[col = ntile*16 + (l&15)][k = kt*32 + (l>>4)*8 + i], i=0..7.
// Blocks [1024,1032): per-channel encoder-LN fold:
//   Wf = gamma*(w-mean(w)), Bf = gamma*(b-mean(b)), st = {var_w, 2cov, var_b}.
__global__ __launch_bounds__(256) void prep_kernel(
    const float* __restrict__ w, __bf16* __restrict__ o,
    const float* __restrict__ enc_w, const float* __restrict__ enc_b,
    const float* __restrict__ enc_gamma,
    float* __restrict__ Wf, float* __restrict__ Bf, float* __restrict__ st)
{
    __shared__ float red[4][5];
    if (blockIdx.x < 1024) {
        int gtid  = blockIdx.x * 256 + threadIdx.x;
        int lane  = gtid & 63;
        int chunk = gtid >> 6;
        int kt    = chunk >> 5;
        int ntile = chunk & 31;
        int col   = ntile * 16 + (lane & 15);
        int k     = kt * 32 + (lane >> 4) * 8;
        const float* src = w + (size_t)col * K_DIM + k;
        float4 a = *(const float4*)src;
        float4 b = *(const float4*)(src + 4);
        bf16x8 h;
        h[0] = (__bf16)a.x; h[1] = (__bf16)a.y; h[2] = (__bf16)a.z; h[3] = (__bf16)a.w;
        h[4] = (__bf16)b.x; h[5] = (__bf16)b.y; h[6] = (__bf16)b.z; h[7] = (__bf16)b.w;
        *(bf16x8*)(o + (size_t)gtid * 8) = h;
    } else {
        const int c = blockIdx.x - 1024;
        const int t = threadIdx.x;
        const float* wp = enc_w + c * H_DIM;
        const float* bp = enc_b + c * H_DIM;
        const float* gp = enc_gamma + c * H_DIM;
        float w0 = wp[t], w1 = wp[t + 256];
        float b0 = bp[t], b1 = bp[t + 256];
        float sw  = w0 + w1;
        float sb  = b0 + b1;
        float sww = fmaf(w0, w0, w1 * w1);
        float sbb = fmaf(b0, b0, b1 * b1);
        float swb = fmaf(w0, b0, w1 * b1);
        #pragma unroll
        for (int off = 32; off; off >>= 1) {
            sw  += __shfl_xor(sw,  off);
            sb  += __shfl_xor(sb,  off);
            sww += __shfl_xor(sww, off);
            sbb += __shfl_xor(sbb, off);
            swb += __shfl_xor(swb, off);
        }
        int wv = t >> 6, ln = t & 63;
        if (ln == 0) {
            red[wv][0] = sw;  red[wv][1] = sb;  red[wv][2] = sww;
            red[wv][3] = sbb; red[wv][4] = swb;
        }
        __syncthreads();
        float tsw  = red[0][0] + red[1][0] + red[2][0] + red[3][0];
        float tsb  = red[0][1] + red[1][1] + red[2][1] + red[3][1];
        float tsww = red[0][2] + red[1][2] + red[2][2] + red[3][2];
        float tsbb = red[0][3] + red[1][3] + red[2][3] + red[3][3];
        float tswb = red[0][4] + red[1][4] + red[2][4] + red[3][4];
        const float inv = 1.0f / (float)H_DIM;
        float mw = tsw * inv, mb = tsb * inv;
        if (t == 0) {
            st[c * 4 + 0] = tsww * inv - mw * mw;
            st[c * 4 + 1] = 2.0f * (tswb * inv - mw * mb);
            st[c * 4 + 2] = tsbb * inv - mb * mb;
        }
        float g0 = gp[t], g1 = gp[t + 256];
        Wf[c * H_DIM + t]       = g0 * (w0 - mw);
        Wf[c * H_DIM + t + 256] = g1 * (w1 - mw);
        Bf[c * H_DIM + t]       = g0 * (b0 - mb);
        Bf[c * H_DIM + t + 256] = g1 * (b1 - mb);
    }
}

// Fused: analytic enc-LN -> gelu -> GEMM(mod_w^T) -> +mod_b -> LayerNorm -> gelu.
// 512 threads / 8 waves, wave-tile 64x64, 16x16x32 MFMA, acc[4][4] (64 AGPR).
// B: per-wave PRIVATE global_load_lds double-buffer (zero VGPR, no cross-wave
// sync). A: computed one k-tile ahead from register-prefetched params (ping-
// pong float4 sets, 1 full k-tile of latency cover), ds_write to A ring.
// Correctness chain: params[kt+1] issued AFTER stageB(kt) (clobber-pinned);
// compiler's wait at params consumption => B[kt] landed (in-order vmcnt);
// B ds_reads clobber-pinned below. Barriers: lgkmcnt-only + raw s_barrier —
// vmcnt never drained in the loop.
template <int USE_WS>
__global__ __launch_bounds__(512, 4) void fused_gemm_kernel(
    const float* __restrict__ x,
    const float* __restrict__ enc_w,
    const float* __restrict__ enc_b,
    const float* __restrict__ enc_gamma,
    const float* __restrict__ enc_beta,
    const float* __restrict__ mod_w,      // fp32 fallback
    const __bf16* __restrict__ Wb,        // bf16 frag-layout (workspace)
    const float* __restrict__ Wf,         // folded gamma*(w-mw)   (workspace)
    const float* __restrict__ Bf,         // folded gamma*(b-mb)   (workspace)
    const float* __restrict__ st,         // per-channel {vw,2cwb,vb} (workspace)
    const float* __restrict__ mod_b,
    const float* __restrict__ mod_gamma,
    const float* __restrict__ mod_beta,
    float* __restrict__ out)
{
    extern __shared__ __align__(16) char smem[];
    float* pSf = (float*)(smem + SMEM_PS);     // [8][64]
    float* qSf = (float*)(smem + SMEM_QS);
    float* statsF = (float*)(smem + SMEM_ST);  // legacy [8][5]
    float* rSf = (float*)(smem + SMEM_BLS + 8192);  // legacy overlay

    const int tid  = threadIdx.x;
    const int wave = tid >> 6;
    const int lane = tid & 63;
    const int lr   = lane & 15;
    const int lq   = lane >> 4;
    const int row0 = blockIdx.x * TM;

    // A-staging decomposition: thread = (mt, slot-lane, half); 4 elems (8B) per kt
    const int smt   = tid >> 7;             // 0..3 (A chunk)
    const int ssl   = (tid >> 1) & 63;      // lane-slot within chunk
    const int shalf = tid & 1;
    const int srow  = smt * 16 + (ssl & 15);
    const int skoff = (ssl >> 4) * 8 + shalf * 4;           // k within tile
    const int sdoff = smt * 1024 + ssl * 16 + shalf * 8;    // byte off in A ring buf

    // ---- p,q (legacy also r) per (channel,row) ----
    if (USE_WS) {
        int c = wave, m = lane;
        float xv = x[c * BS + row0 + m];
        float vw = st[c * 4 + 0], cwb2 = st[c * 4 + 1], vb = st[c * 4 + 2];
        float q = rsqrtf(fmaf(xv, fmaf(xv, vw, cwb2), vb) + EPS);
        pSf[c * TM + m] = xv * q;
        qSf[c * TM + m] = q;
    } else {
        {
            const int c = wave;
            float sw = 0.f, sb = 0.f, sww = 0.f, sbb = 0.f, swb = 0.f;
            for (int jj = lane; jj < H_DIM; jj += 64) {
                float w = enc_w[c * H_DIM + jj];
                float b = enc_b[c * H_DIM + jj];
                sw += w; sb += b;
                sww = fmaf(w, w, sww);
                sbb = fmaf(b, b, sbb);
                swb = fmaf(w, b, swb);
            }
            #pragma unroll
            for (int off = 32; off; off >>= 1) {
                sw  += __shfl_xor(sw,  off);
                sb  += __shfl_xor(sb,  off);
                sww += __shfl_xor(sww, off);
                sbb += __shfl_xor(sbb, off);
                swb += __shfl_xor(swb, off);
            }
            if (lane == 0) {
                const float inv = 1.0f / (float)H_DIM;
                float mw = sw * inv, mb = sb * inv;
                statsF[c * 5 + 0] = mw;
                statsF[c * 5 + 1] = mb;
                statsF[c * 5 + 2] = sww * inv - mw * mw;
                statsF[c * 5 + 3] = sbb * inv - mb * mb;
                statsF[c * 5 + 4] = swb * inv - mw * mb;
            }
        }
        __syncthreads();
        {
            int c = wave, m = lane;
            float xv = x[c * BS + row0 + m];
            float mw = statsF[c * 5 + 0], mb = statsF[c * 5 + 1];
            float vw = statsF[c * 5 + 2], vb = statsF[c * 5 + 3], cwb = statsF[c * 5 + 4];
            float var = fmaf(xv, fmaf(xv, vw, 2.0f * cwb), vb);
            float q = rsqrtf(var + EPS);
            float p = xv * q;
            pSf[c * TM + m] = p;
            qSf[c * TM + m] = q;
            rSf[c * TM + m] = -fmaf(p, mw, q * mb);
        }
    }
    __syncthreads();

    floatx4 acc[4][4];
    #pragma unroll
    for (int i = 0; i < 4; ++i)
        #pragma unroll
        for (int j = 0; j < 4; ++j)
            acc[i][j] = (floatx4){0.f, 0.f, 0.f, 0.f};

    // ---- B stage: wave's 4 chunks of k-tile j -> Bls ring (j&1), async ----
    auto stageB = [&](int j) {
        const int r = j & 1;
        #pragma unroll
        for (int nt = 0; nt < 4; ++nt) {
            const int chunk = j * 32 + wave * 4 + nt;
            const char* g = (const char*)Wb + (size_t)chunk * 1024 + lane * 16;
            void* l = smem + SMEM_BLS + r * 32768 + (wave * 4 + nt) * 1024;
            gld_lds16(g, l);
        }
    };

    // ---- A compute: 4 elems from param regs -> A ring (j&1) ----
    auto computeA = [&](int j, float4 w, float4 b, float4 e, float p, float q) {
        float fw[4] = {w.x, w.y, w.z, w.w};
        float fb[4] = {b.x, b.y, b.z, b.w};
        float fe[4] = {e.x, e.y, e.z, e.w};
        bf16x4 hv;
        #pragma unroll
        for (int i = 0; i < 4; ++i) {
            float v = fmaf(p, fw[i], fmaf(q, fb[i], fe[i]));
            hv[i] = (__bf16)gelu_fast(v);
        }
        *(bf16x4*)(smem + SMEM_ALS + (j & 1) * 4096 + sdoff) = hv;
    };

    // ---- MFMA phase for k-tile kt: A/B frags from LDS rings ----
    auto mfmaPhase = [&](int kt) {
        const __bf16* Ab = (const __bf16*)(smem + SMEM_ALS + (kt & 1) * 4096);
        const char*   Bb = smem + SMEM_BLS + (kt & 1) * 32768 + wave * 4096;
        bf16x8 af0 = *(const bf16x8*)(Ab + 0 * 512 + lane * 8);
        bf16x8 af1 = *(const bf16x8*)(Ab + 1 * 512 + lane * 8);
        bf16x8 af2 = *(const bf16x8*)(Ab + 2 * 512 + lane * 8);
        bf16x8 af3 = *(const bf16x8*)(Ab + 3 * 512 + lane * 8);
        bf16x8 b0 = *(const bf16x8*)(Bb + 0 * 1024 + lane * 16);
        bf16x8 b1 = *(const bf16x8*)(Bb + 1 * 1024 + lane * 16);
        __builtin_amdgcn_s_setprio(1);
        acc[0][0] = __builtin_amdgcn_mfma_f32_16x16x32_bf16(af0, b0, acc[0][0], 0, 0, 0);
        acc[1][0] = __builtin_amdgcn_mfma_f32_16x16x32_bf16(af1, b0, acc[1][0], 0, 0, 0);
        acc[2][0] = __builtin_amdgcn_mfma_f32_16x16x32_bf16(af2, b0, acc[2][0], 0, 0, 0);
        acc[3][0] = __builtin_amdgcn_mfma_f32_16x16x32_bf16(af3, b0, acc[3][0], 0, 0, 0);
        acc[0][1] = __builtin_amdgcn_mfma_f32_16x16x32_bf16(af0, b1, acc[0][1], 0, 0, 0);
        acc[1][1] = __builtin_amdgcn_mfma_f32_16x16x32_bf16(af1, b1, acc[1][1], 0, 0, 0);
        acc[2][1] = __builtin_amdgcn_mfma_f32_16x16x32_bf16(af2, b1, acc[2][1], 0, 0, 0);
        acc[3][1] = __builtin_amdgcn_mfma_f32_16x16x32_bf16(af3, b1, acc[3][1], 0, 0, 0);
        __builtin_amdgcn_s_setprio(0);
        b0 = *(const bf16x8*)(Bb + 2 * 1024 + lane * 16);
        b1 = *(const bf16x8*)(Bb + 3 * 1024 + lane * 16);
        __builtin_amdgcn_s_setprio(1);
        acc[0][2] = __builtin_amdgcn_mfma_f32_16x16x32_bf16(af0, b0, acc[0][2], 0, 0, 0);
        acc[1][2] = __builtin_amdgcn_mfma_f32_16x16x32_bf16(af1, b0, acc[1][2], 0, 0, 0);
        acc[2][2] = __builtin_amdgcn_mfma_f32_16x16x32_bf16(af2, b0, acc[2][2], 0, 0, 0);
        acc[3][2] = __builtin_amdgcn_mfma_f32_16x16x32_bf16(af3, b0, acc[3][2], 0, 0, 0);
        acc[0][3] = __builtin_amdgcn_mfma_f32_16x16x32_bf16(af0, b1, acc[0][3], 0, 0, 0);
        acc[1][3] = __builtin_amdgcn_mfma_f32_16x16x32_bf16(af1, b1, acc[1][3], 0, 0, 0);
        acc[2][3] = __builtin_amdgcn_mfma_f32_16x16x32_bf16(af2, b1, acc[2][3], 0, 0, 0);
        acc[3][3] = __builtin_amdgcn_mfma_f32_16x16x32_bf16(af3, b1, acc[3][3], 0, 0, 0);
        __builtin_amdgcn_s_setprio(0);
    };

    if (USE_WS) {
        float pCur = pSf[srow];        // channel 0
        float qCur = qSf[srow];
        float4 paW, paB, paE, pbW, pbB, pbE;

        // prologue: B[0] in flight; P[0] loaded after (clobber-pinned) so its
        // consumption below implies B[0] landed; A[0] staged; P[1] in flight.
        stageB(0);
        asm volatile("" ::: "memory");
        paW = *(const float4*)(Wf + skoff);
        paB = *(const float4*)(Bf + skoff);
        paE = *(const float4*)(enc_beta + skoff);
        asm volatile("" ::: "memory");
        computeA(0, paW, paB, paE, pCur, qCur);
        pbW = *(const float4*)(Wf + TK + skoff);
        pbB = *(const float4*)(Bf + TK + skoff);
        pbE = *(const float4*)(enc_beta + TK + skoff);
        asm volatile("s_waitcnt lgkmcnt(0)" ::: "memory");
        __builtin_amdgcn_s_barrier();
        __builtin_amdgcn_sched_barrier(0);

        // iteration kt: stage B[kt+1]; issue params[kt+2] -> n*; compute
        // A[kt+1] from c* (its wait => B[kt] done); MFMA(kt); raw barrier.
        auto fiter = [&](int kt, float4& cw, float4& cb, float4& ce,
                         float4& nw, float4& nb, float4& ne) {
            if (kt + 1 < NKT) stageB(kt + 1);
            asm volatile("" ::: "memory");
            if (kt + 2 < NKT) {
                nw = *(const float4*)(Wf + (kt + 2) * TK + skoff);
                nb = *(const float4*)(Bf + (kt + 2) * TK + skoff);
                ne = *(const float4*)(enc_beta + (kt + 2) * TK + skoff);
            }
            asm volatile("" ::: "memory");
            if (kt + 1 < NKT) {
                if (((kt + 1) & 15) == 0) {          // channel boundary
                    pCur = pSf[((kt + 1) >> 4) * TM + srow];
                    qCur = qSf[((kt + 1) >> 4) * TM + srow];
                }
                computeA(kt + 1, cw, cb, ce, pCur, qCur);
            }
            asm volatile("" ::: "memory");
            if (kt == NKT - 1)                       // no param-wait exists for B[127]
                asm volatile("s_waitcnt vmcnt(0)" ::: "memory");
            mfmaPhase(kt);
            asm volatile("s_waitcnt lgkmcnt(0)" ::: "memory");
            __builtin_amdgcn_s_barrier();
            __builtin_amdgcn_sched_barrier(0);
        };

        for (int kt = 0; kt < NKT; kt += 2) {
            fiter(kt,     pbW, pbB, pbE, paW, paB, paE);
            fiter(kt + 1, paW, paB, paE, pbW, pbB, pbE);
        }
    } else {
        // legacy: simple single-buffer A, B from mod_w (correctness-only path)
        for (int kt = 0; kt < NKT; ++kt) {
            {
                int c = kt >> 4;
                float p = pSf[c * TM + srow], q = qSf[c * TM + srow], r = rSf[c * TM + srow];
                int k0 = kt * TK + skoff;
                float4 w = *(const float4*)(enc_w + k0);
                float4 b = *(const float4*)(enc_b + k0);
                float4 g = *(const float4*)(enc_gamma + k0);
                float4 e = *(const float4*)(enc_beta + k0);
                float fw[4] = {w.x, w.y, w.z, w.w};
                float fb[4] = {b.x, b.y, b.z, b.w};
                float fg[4] = {g.x, g.y, g.z, g.w};
                float fe[4] = {e.x, e.y, e.z, e.w};
                bf16x4 hv;
                #pragma unroll
                for (int i = 0; i < 4; ++i) {
                    float t = fmaf(p, fw[i], fmaf(q, fb[i], r));
                    float v = fmaf(t, fg[i], fe[i]);
                    hv[i] = (__bf16)gelu_fast(v);
                }
                *(bf16x4*)(smem + SMEM_ALS + sdoff) = hv;
            }
            __syncthreads();
            {
                const __bf16* Ab = (const __bf16*)(smem + SMEM_ALS);
                bf16x8 af[4];
                #pragma unroll
                for (int mt = 0; mt < 4; ++mt)
                    af[mt] = *(const bf16x8*)(Ab + mt * 512 + lane * 8);
                #pragma unroll
                for (int nt = 0; nt < 4; ++nt) {
                    int col = wave * 64 + nt * 16 + lr;
                    int kk  = kt * 32 + lq * 8;
                    const float* src = mod_w + (size_t)col * K_DIM + kk;
                    float4 a = *(const float4*)src;
                    float4 b2 = *(const float4*)(src + 4);
                    bf16x8 bb;
                    bb[0] = (__bf16)a.x;  bb[1] = (__bf16)a.y;
                    bb[2] = (__bf16)a.z;  bb[3] = (__bf16)a.w;
                    bb[4] = (__bf16)b2.x; bb[5] = (__bf16)b2.y;
                    bb[6] = (__bf16)b2.z; bb[7] = (__bf16)b2.w;
                    #pragma unroll
                    for (int mt = 0; mt < 4; ++mt)
                        acc[mt][nt] = __builtin_amdgcn_mfma_f32_16x16x32_bf16(
                            af[mt], bb, acc[mt][nt], 0, 0, 0);
                }
            }
            __syncthreads();
        }
    }

    // ---- drain all async ops, then overlay epilogue arrays into BLS ----
    asm volatile("s_waitcnt vmcnt(0) lgkmcnt(0)" ::: "memory");
    __syncthreads();
    float* redS = (float*)(smem + SMEM_BLS);          // [64][8]
    float* redQ = (float*)(smem + SMEM_BLS + 2048);   // [64][8]
    float* muS  = (float*)(smem + SMEM_BLS + 4096);   // [64]
    float* invS = (float*)(smem + SMEM_BLS + 4352);   // [64]

    // ---- fused epilogue: +mod_b, LayerNorm over 512 cols, gelu, store ----
    float mbv[4], gv[4], bev[4];
    #pragma unroll
    for (int nt = 0; nt < 4; ++nt) {
        int col = wave * 64 + nt * 16 + lr;
        mbv[nt] = mod_b[col];
        gv[nt]  = mod_gamma[col];
        bev[nt] = mod_beta[col];
    }
    #pragma unroll
    for (int mt = 0; mt < 4; ++mt)
        #pragma unroll
        for (int nt = 0; nt < 4; ++nt)
            #pragma unroll
            for (int r = 0; r < 4; ++r)
                acc[mt][nt][r] += mbv[nt];

    #pragma unroll
    for (int mt = 0; mt < 4; ++mt) {
        #pragma unroll
        for (int r = 0; r < 4; ++r) {
            float s = 0.f, ss = 0.f;
            #pragma unroll
            for (int nt = 0; nt < 4; ++nt) {
                float y = acc[mt][nt][r];
                s += y;
                ss = fmaf(y, y, ss);
            }
            #pragma unroll
            for (int off = 1; off < 16; off <<= 1) {
                s  += __shfl_xor(s,  off);
                ss += __shfl_xor(ss, off);
            }
            if (lr == 0) {
                int row = mt * 16 + lq * 4 + r;
                redS[row * 8 + wave] = s;
                redQ[row * 8 + wave] = ss;
            }
        }
    }
    __syncthreads();
    if (tid < TM) {
        float s = 0.f, ss = 0.f;
        #pragma unroll
        for (int w = 0; w < 8; ++w) {
            s  += redS[tid * 8 + w];
            ss += redQ[tid * 8 + w];
        }
        const float inv_n = 1.0f / (float)H_DIM;
        float mu  = s * inv_n;
        float var = ss * inv_n - mu * mu;
        muS[tid]  = mu;
        invS[tid] = rsqrtf(var + EPS);
    }
    __syncthreads();

    #pragma unroll
    for (int mt = 0; mt < 4; ++mt) {
        #pragma unroll
        for (int r = 0; r < 4; ++r) {
            int row = mt * 16 + lq * 4 + r;
            float mu  = muS[row];
            float inv = invS[row];
            float* op = out + (size_t)(row0 + row) * H_DIM;
            #pragma unroll
            for (int nt = 0; nt < 4; ++nt) {
                int col = wave * 64 + nt * 16 + lr;
                float t = fmaf((acc[mt][nt][r] - mu) * inv, gv[nt], bev[nt]);
                op[col] = gelu_fast(t);
            }
        }
    }
}

extern "C" void kernel_launch(void* const* d_in, const int* in_sizes, int n_in,
                              void* d_out, int out_size, void* d_ws, size_t ws_size,
                              hipStream_t stream) {
    const float* x         = (const float*)d_in[0];
    const float* enc_w     = (const float*)d_in[1];
    const float* enc_b     = (const float*)d_in[2];
    const float* enc_gamma = (const float*)d_in[3];
    const float* enc_beta  = (const float*)d_in[4];
    const float* mod_w     = (const float*)d_in[5];
    const float* mod_b     = (const float*)d_in[6];
    const float* mod_gamma = (const float*)d_in[7];
    const float* mod_beta  = (const float*)d_in[8];
    float* out = (float*)d_out;

    const size_t wb_bytes = (size_t)H_DIM * K_DIM * sizeof(__bf16);   // 4 MB
    const size_t wf_off   = wb_bytes;
    const size_t bf_off   = wf_off + (size_t)C_CH * H_DIM * sizeof(float);
    const size_t st_off   = bf_off + (size_t)C_CH * H_DIM * sizeof(float);
    const size_t need     = st_off + (size_t)C_CH * 4 * sizeof(float);

    int use_ws = (ws_size >= need) ? 1 : 0;
    __bf16* Wb = (__bf16*)d_ws;
    float*  Wf = (float*)((char*)d_ws + wf_off);
    float*  Bf = (float*)((char*)d_ws + bf_off);
    float*  st = (float*)((char*)d_ws + st_off);

    static int attr_done = 0;
    if (!attr_done) {
        hipFuncSetAttribute((const void*)fused_gemm_kernel<1>,
                            hipFuncAttributeMaxDynamicSharedMemorySize, SMEM_SZ);
        hipFuncSetAttribute((const void*)fused_gemm_kernel<0>,
                            hipFuncAttributeMaxDynamicSharedMemorySize, SMEM_SZ);
        attr_done = 1;
    }

    if (use_ws) {
        prep_kernel<<<1024 + C_CH, 256, 0, stream>>>(
            mod_w, Wb, enc_w, enc_b, enc_gamma, Wf, Bf, st);
        fused_gemm_kernel<1><<<BS / TM, 512, SMEM_SZ, stream>>>(
            x, enc_w, enc_b, enc_gamma, enc_beta, mod_w, Wb, Wf, Bf, st,
            mod_b, mod_gamma, mod_beta, out);
    } else {
        fused_gemm_kernel<0><<<BS / TM, 512, SMEM_SZ, stream>>>(
            x, enc_w, enc_b, enc_gamma, enc_beta, mod_w, Wb,
            (const float*)0, (const float*)0, (const float*)0,
            mod_b, mod_gamma, mod_beta, out);
    }
}

// Round 11
// 249.592 us; speedup vs baseline: 1.9556x; 1.9556x over previous
//
#include <hip/hip_runtime.h>
#include <hip/hip_bf16.h>
#include <math.h>

#define C_CH 8
#define H_DIM 512
#define BS 32768            // B*S
#define K_DIM 4096          // C*H
#define EPS 1e-5f

#define TM 64
#define TK 32
#define NKT (K_DIM / TK)    // 128 K-tiles
#define GRP 8               // k-tiles per barrier group (R1 had 4)
#define NGRP (NKT / GRP)    // 16 groups
#define TMTK (TM * TK)      // 2048 elems / 4 KB per sub-tile

typedef __bf16 bf16x8 __attribute__((ext_vector_type(8)));
typedef __bf16 bf16x4 __attribute__((ext_vector_type(4)));
typedef float  floatx4 __attribute__((ext_vector_type(4)));

// Dynamic-LDS layout (76.4 KB; 2 blocks/CU: 152.9 KB < 160 KB):
//   ALS  [2 rings][8 sub-tiles][4 KB] = 65536  (A frags, XOR-swizzled chunks)
//   PS/QS/RS [8][64] f32 each         = 6144
//   ST   legacy stats [8][5]          = 160 (+pad)
//   REDS/REDQ [64][8] f32             = 4096
//   MUS/INVS [64] f32                 = 512
#define SM_ALS   0
#define SM_PS    65536
#define SM_QS    67584
#define SM_RS    69632
#define SM_ST    71680
#define SM_REDS  71840
#define SM_REDQ  73888
#define SM_MUS   75936
#define SM_INVS  76192
#define SM_SZ    76448

// tanh-form GELU, exp2-folded; max abs dev from exact erf-gelu ~3e-4.
__device__ __forceinline__ float gelu_fast(float v) {
    float x2 = v * fmaf(v * v, 0.102943215f, 2.30220815f);   // x*log2e
    float e = __builtin_amdgcn_exp2f(-x2);
    return v * __builtin_amdgcn_rcpf(1.0f + e);
}

// Prep kernel, grid = 1024 + 8 blocks x 256 threads.
// Blocks [0,1024): mod_w fp32 [512][4096] -> bf16 workspace in MFMA B-fragment
//   chunk layout: chunk(kt 0..127, ntile 0..31) of 64 lanes x 16B; lane l holds
//   B[col = ntile*16 + (l&15)][k = kt*32 + (l>>4)*8 + i], i=0..7.
// Blocks [1024,1032): per-channel encoder-LN fold:
//   Wf = gamma*(w-mean(w)), Bf = gamma*(b-mean(b)), st = {var_w, 2cov, var_b}.
__global__ __launch_bounds__(256) void prep_kernel(
    const float* __restrict__ w, __bf16* __restrict__ o,
    const float* __restrict__ enc_w, const float* __restrict__ enc_b,
    const float* __restrict__ enc_gamma,
    float* __restrict__ Wf, float* __restrict__ Bf, float* __restrict__ st)
{
    __shared__ float red[4][5];
    if (blockIdx.x < 1024) {
        int gtid  = blockIdx.x * 256 + threadIdx.x;   // 0..262143
        int lane  = gtid & 63;
        int chunk = gtid >> 6;                        // 0..4095
        int kt    = chunk >> 5;
        int ntile = chunk & 31;
        int col   = ntile * 16 + (lane & 15);
        int k     = kt * 32 + (lane >> 4) * 8;
        const float* src = w + (size_t)col * K_DIM + k;
        float4 a = *(const float4*)src;
        float4 b = *(const float4*)(src + 4);
        bf16x8 h;
        h[0] = (__bf16)a.x; h[1] = (__bf16)a.y; h[2] = (__bf16)a.z; h[3] = (__bf16)a.w;
        h[4] = (__bf16)b.x; h[5] = (__bf16)b.y; h[6] = (__bf16)b.z; h[7] = (__bf16)b.w;
        *(bf16x8*)(o + (size_t)gtid * 8) = h;
    } else {
        const int c = blockIdx.x - 1024;              // 0..7
        const int t = threadIdx.x;                    // 0..255
        const float* wp = enc_w + c * H_DIM;
        const float* bp = enc_b + c * H_DIM;
        const float* gp = enc_gamma + c * H_DIM;
        float w0 = wp[t], w1 = wp[t + 256];
        float b0 = bp[t], b1 = bp[t + 256];
        float sw  = w0 + w1;
        float sb  = b0 + b1;
        float sww = fmaf(w0, w0, w1 * w1);
        float sbb = fmaf(b0, b0, b1 * b1);
        float swb = fmaf(w0, b0, w1 * b1);
        #pragma unroll
        for (int off = 32; off; off >>= 1) {
            sw  += __shfl_xor(sw,  off);
            sb  += __shfl_xor(sb,  off);
            sww += __shfl_xor(sww, off);
            sbb += __shfl_xor(sbb, off);
            swb += __shfl_xor(swb, off);
        }
        int wv = t >> 6, ln = t & 63;
        if (ln == 0) {
            red[wv][0] = sw;  red[wv][1] = sb;  red[wv][2] = sww;
            red[wv][3] = sbb; red[wv][4] = swb;
        }
        __syncthreads();
        float tsw  = red[0][0] + red[1][0] + red[2][0] + red[3][0];
        float tsb  = red[0][1] + red[1][1] + red[2][1] + red[3][1];
        float tsww = red[0][2] + red[1][2] + red[2][2] + red[3][2];
        float tsbb = red[0][3] + red[1][3] + red[2][3] + red[3][3];
        float tswb = red[0][4] + red[1][4] + red[2][4] + red[3][4];
        const float inv = 1.0f / (float)H_DIM;
        float mw = tsw * inv, mb = tsb * inv;
        if (t == 0) {
            st[c * 4 + 0] = tsww * inv - mw * mw;           // var_w
            st[c * 4 + 1] = 2.0f * (tswb * inv - mw * mb);  // 2*cov
            st[c * 4 + 2] = tsbb * inv - mb * mb;           // var_b
        }
        float g0 = gp[t], g1 = gp[t + 256];
        Wf[c * H_DIM + t]       = g0 * (w0 - mw);
        Wf[c * H_DIM + t + 256] = g1 * (w1 - mw);
        Bf[c * H_DIM + t]       = g0 * (b0 - mb);
        Bf[c * H_DIM + t + 256] = g1 * (b1 - mb);
    }
}

// Fused: analytic enc-LN -> gelu -> GEMM(mod_w^T) -> +mod_b -> LayerNorm -> gelu.
// R1's proven schedule (512 thr / 8 waves, wave-tile 64x64, 16x16x32 MFMA,
// per-sub stageA/loadB/MFMA interleave, P/Q B-frag rotation) with ONE change:
// GRP 4 -> 8 (one barrier per 8 k-tiles instead of 4). Register footprint
// identical to R1 (64 VGPR + 64 AGPR); A-ring doubles to 64 KB via dynamic LDS.
template <int USE_WS>
__global__ __launch_bounds__(512, 4) void fused_gemm_kernel(
    const float* __restrict__ x,
    const float* __restrict__ enc_w,
    const float* __restrict__ enc_b,
    const float* __restrict__ enc_gamma,
    const float* __restrict__ enc_beta,
    const float* __restrict__ mod_w,      // fp32 fallback
    const __bf16* __restrict__ Wb,        // bf16 frag-layout (workspace)
    const float* __restrict__ Wf,         // folded gamma*(w-mw)   (workspace)
    const float* __restrict__ Bf,         // folded gamma*(b-mb)   (workspace)
    const float* __restrict__ st,         // per-channel {vw,2cwb,vb} (workspace)
    const float* __restrict__ mod_b,
    const float* __restrict__ mod_gamma,
    const float* __restrict__ mod_beta,
    float* __restrict__ out)
{
    extern __shared__ __align__(16) char smem[];
    __bf16* Als   = (__bf16*)(smem + SM_ALS);
    float*  pS    = (float*)(smem + SM_PS);    // [8][64]
    float*  qS    = (float*)(smem + SM_QS);
    float*  rS    = (float*)(smem + SM_RS);    // legacy only
    float*  stats = (float*)(smem + SM_ST);    // legacy [8][5]

    const int tid  = threadIdx.x;
    const int wave = tid >> 6;        // 0..7
    const int lane = tid & 63;
    const int lr   = lane & 15;
    const int lq   = lane >> 4;
    const int row0 = blockIdx.x * TM;

    // ---- per-(channel,row) p,q (legacy also r) ----
    if (USE_WS) {
        int c = wave, m = lane;       // 512 threads == 8 channels x 64 rows
        float xv = x[c * BS + row0 + m];
        float vw = st[c * 4 + 0], cwb2 = st[c * 4 + 1], vb = st[c * 4 + 2];
        float q = rsqrtf(fmaf(xv, fmaf(xv, vw, cwb2), vb) + EPS);
        pS[c * TM + m] = xv * q;
        qS[c * TM + m] = q;
    } else {
        {
            const int c = wave;
            float sw = 0.f, sb = 0.f, sww = 0.f, sbb = 0.f, swb = 0.f;
            for (int j = lane; j < H_DIM; j += 64) {
                float w = enc_w[c * H_DIM + j];
                float b = enc_b[c * H_DIM + j];
                sw += w; sb += b;
                sww = fmaf(w, w, sww);
                sbb = fmaf(b, b, sbb);
                swb = fmaf(w, b, swb);
            }
            #pragma unroll
            for (int off = 32; off; off >>= 1) {
                sw  += __shfl_xor(sw,  off);
                sb  += __shfl_xor(sb,  off);
                sww += __shfl_xor(sww, off);
                sbb += __shfl_xor(sbb, off);
                swb += __shfl_xor(swb, off);
            }
            if (lane == 0) {
                const float inv = 1.0f / (float)H_DIM;
                float mw = sw * inv, mb = sb * inv;
                stats[c * 5 + 0] = mw;
                stats[c * 5 + 1] = mb;
                stats[c * 5 + 2] = sww * inv - mw * mw;
                stats[c * 5 + 3] = sbb * inv - mb * mb;
                stats[c * 5 + 4] = swb * inv - mw * mb;
            }
        }
        __syncthreads();
        {
            int c = wave, m = lane;
            float xv = x[c * BS + row0 + m];
            float mw = stats[c * 5 + 0], mb = stats[c * 5 + 1];
            float vw = stats[c * 5 + 2], vb = stats[c * 5 + 3], cwb = stats[c * 5 + 4];
            float var = fmaf(xv, fmaf(xv, vw, 2.0f * cwb), vb);
            float q = rsqrtf(var + EPS);
            float p = xv * q;
            pS[c * TM + m] = p;
            qS[c * TM + m] = q;
            rS[c * TM + m] = -fmaf(p, mw, q * mb);
        }
    }
    __syncthreads();

    const int wn = wave;             // wave tile: 64 rows x 64 cols

    // stageA decomposition: tid = row*8 + kq*2 + half (4 elems / 8B per thread)
    const int arow  = tid >> 3;      // 0..63
    const int akq   = (tid >> 1) & 3;
    const int ahalf = tid & 1;
    const int wchunk = arow * 4 + (akq ^ ((arow >> 1) & 3));   // XOR bank swizzle

    floatx4 acc[4][4];
    #pragma unroll
    for (int i = 0; i < 4; ++i)
        #pragma unroll
        for (int j = 0; j < 4; ++j)
            acc[i][j] = (floatx4){0.f, 0.f, 0.f, 0.f};

    // ---- A-stage (folded): v = p*Wf + q*Bf + beta; gelu; one 8B half-chunk ----
    auto stageA2 = [&](int ktn, __bf16* dst, float p, float q) {
        const int j0 = ktn * TK + akq * 8 + ahalf * 4;   // Wf/Bf/beta are [C*H]
        float4 w = *(const float4*)(Wf + j0);
        float4 b = *(const float4*)(Bf + j0);
        float4 e = *(const float4*)(enc_beta + j0);
        float fw[4] = {w.x, w.y, w.z, w.w};
        float fb[4] = {b.x, b.y, b.z, b.w};
        float fe[4] = {e.x, e.y, e.z, e.w};
        bf16x4 hv;
        #pragma unroll
        for (int i = 0; i < 4; ++i) {
            float v = fmaf(p, fw[i], fmaf(q, fb[i], fe[i]));
            hv[i] = (__bf16)gelu_fast(v);
        }
        *(bf16x4*)(dst + wchunk * 8 + ahalf * 4) = hv;
    };

    // ---- legacy A-stage: 4 param arrays + r term ----
    auto stageA_legacy = [&](int ktn, __bf16* dst, float p, float q, float r) {
        const int j0 = ktn * TK + akq * 8 + ahalf * 4;
        float4 w = *(const float4*)(enc_w + j0);
        float4 b = *(const float4*)(enc_b + j0);
        float4 g = *(const float4*)(enc_gamma + j0);
        float4 e = *(const float4*)(enc_beta + j0);
        float fw[4] = {w.x, w.y, w.z, w.w};
        float fb[4] = {b.x, b.y, b.z, b.w};
        float fg[4] = {g.x, g.y, g.z, g.w};
        float fe[4] = {e.x, e.y, e.z, e.w};
        bf16x4 hv;
        #pragma unroll
        for (int i = 0; i < 4; ++i) {
            float t = fmaf(p, fw[i], fmaf(q, fb[i], r));
            float v = fmaf(t, fg[i], fe[i]);
            hv[i] = (__bf16)gelu_fast(v);
        }
        *(bf16x4*)(dst + wchunk * 8 + ahalf * 4) = hv;
    };

    // ---- B-frag loader: 2 frags (one n-half of the wave's 64 cols) ----
    const __bf16* baseB = Wb + ((size_t)(wn * 4) * 64 + lane) * 8;
    auto loadB = [&](int ktn, int half, bf16x8* dst) {
        if (USE_WS) {
            const __bf16* bp = baseB + ktn * 16384 + half * 1024;
            dst[0] = *(const bf16x8*)(bp);
            dst[1] = *(const bf16x8*)(bp + 512);
        } else {
            const int kk = ktn * 32 + lq * 8;
            #pragma unroll
            for (int nt = 0; nt < 2; ++nt) {
                int col = wn * 64 + (half * 2 + nt) * 16 + lr;
                const float* src = mod_w + (size_t)col * K_DIM + kk;
                float4 a = *(const float4*)src;
                float4 b = *(const float4*)(src + 4);
                bf16x8 h;
                h[0] = (__bf16)a.x; h[1] = (__bf16)a.y; h[2] = (__bf16)a.z; h[3] = (__bf16)a.w;
                h[4] = (__bf16)b.x; h[5] = (__bf16)b.y; h[6] = (__bf16)b.z; h[7] = (__bf16)b.w;
                dst[nt] = h;
            }
        }
    };

    bf16x8 bfrP[2], bfrQ[2];
    loadB(0, 0, bfrP);          // prologue: first half of k-tile-0 B in flight
    {
        float p0 = pS[arow], q0 = qS[arow];          // channel 0
        if (USE_WS) {
            #pragma unroll
            for (int sub = 0; sub < GRP; ++sub)
                stageA2(sub, Als + sub * TMTK, p0, q0);
        } else {
            float r0 = rS[arow];
            #pragma unroll
            for (int sub = 0; sub < GRP; ++sub)
                stageA_legacy(sub, Als + sub * TMTK, p0, q0, r0);
        }
    }
    __syncthreads();

    for (int g = 0; g < NGRP; ++g) {
        const __bf16* cur = Als + (g & 1) * (GRP * TMTK);
        __bf16*       nxt = Als + ((g + 1) & 1) * (GRP * TMTK);
        const bool haveNext = (g + 1 < NGRP);

        float pC = 0.f, qC = 0.f, rC = 0.f;
        if (haveNext) {
            const int cn = (g + 1) >> 1;   // 8 kt/group, 16 kt/channel
            pC = pS[cn * TM + arow];
            qC = qS[cn * TM + arow];
            if (!USE_WS) rC = rS[cn * TM + arow];
        }

        #pragma unroll
        for (int sub = 0; sub < GRP; ++sub) {
            const int kt = g * GRP + sub;

            // second-half B for this k-tile (covered by stageA VALU below)
            loadB(kt, 1, bfrQ);

            // stage one sub-tile of the NEXT group's A
            if (haveNext) {
                if (USE_WS) stageA2(kt + GRP, nxt + sub * TMTK, pC, qC);
                else        stageA_legacy(kt + GRP, nxt + sub * TMTK, pC, qC, rC);
            }

            // A fragment reads (swizzled, 2-way conflict = free)
            const __bf16* Acur = cur + sub * TMTK;
            bf16x8 af[4];
            #pragma unroll
            for (int mt = 0; mt < 4; ++mt) {
                int row = mt * 16 + lr;
                int chunk = row * 4 + (lq ^ ((row >> 1) & 3));
                af[mt] = *(const bf16x8*)(Acur + chunk * 8);
            }

            // MFMA half 1: bfrP (issued one phase earlier)
            #pragma unroll
            for (int mt = 0; mt < 4; ++mt)
                #pragma unroll
                for (int nt = 0; nt < 2; ++nt)
                    acc[mt][nt] = __builtin_amdgcn_mfma_f32_16x16x32_bf16(
                        af[mt], bfrP[nt], acc[mt][nt], 0, 0, 0);

            // first-half B for the NEXT k-tile
            if (kt + 1 < NKT) loadB(kt + 1, 0, bfrP);

            // MFMA half 2: bfrQ
            #pragma unroll
            for (int mt = 0; mt < 4; ++mt)
                #pragma unroll
                for (int nt = 0; nt < 2; ++nt)
                    acc[mt][nt + 2] = __builtin_amdgcn_mfma_f32_16x16x32_bf16(
                        af[mt], bfrQ[nt], acc[mt][nt + 2], 0, 0, 0);
        }
        __syncthreads();      // ONE barrier per 8 k-tiles (R1: per 4)
    }

    // ---- fused epilogue: +mod_b, LayerNorm over 512 cols, gelu, store ----
    float* redS = (float*)(smem + SM_REDS);   // [64][8]
    float* redQ = (float*)(smem + SM_REDQ);
    float* muS  = (float*)(smem + SM_MUS);
    float* invS = (float*)(smem + SM_INVS);

    float mbv[4], gv[4], bev[4];
    #pragma unroll
    for (int nt = 0; nt < 4; ++nt) {
        int col = wn * 64 + nt * 16 + lr;
        mbv[nt] = mod_b[col];
        gv[nt]  = mod_gamma[col];
        bev[nt] = mod_beta[col];
    }
    #pragma unroll
    for (int mt = 0; mt < 4; ++mt)
        #pragma unroll
        for (int nt = 0; nt < 4; ++nt)
            #pragma unroll
            for (int r = 0; r < 4; ++r)
                acc[mt][nt][r] += mbv[nt];

    // per-row partial sums within this wave's 64 cols
    #pragma unroll
    for (int mt = 0; mt < 4; ++mt) {
        #pragma unroll
        for (int r = 0; r < 4; ++r) {
            float s = 0.f, ss = 0.f;
            #pragma unroll
            for (int nt = 0; nt < 4; ++nt) {
                float y = acc[mt][nt][r];
                s += y;
                ss = fmaf(y, y, ss);
            }
            #pragma unroll
            for (int off = 1; off < 16; off <<= 1) {
                s  += __shfl_xor(s,  off);
                ss += __shfl_xor(ss, off);
            }
            if (lr == 0) {
                int row = mt * 16 + lq * 4 + r;
                redS[row * 8 + wn] = s;
                redQ[row * 8 + wn] = ss;
            }
        }
    }
    __syncthreads();
    if (tid < TM) {
        float s = 0.f, ss = 0.f;
        #pragma unroll
        for (int w = 0; w < 8; ++w) {
            s  += redS[tid * 8 + w];
            ss += redQ[tid * 8 + w];
        }
        const float inv_n = 1.0f / (float)H_DIM;
        float mu  = s * inv_n;
        float var = ss * inv_n - mu * mu;
        muS[tid]  = mu;
        invS[tid] = rsqrtf(var + EPS);
    }
    __syncthreads();

    #pragma unroll
    for (int mt = 0; mt < 4; ++mt) {
        #pragma unroll
        for (int r = 0; r < 4; ++r) {
            int row = mt * 16 + lq * 4 + r;
            float mu  = muS[row];
            float inv = invS[row];
            float* op = out + (size_t)(row0 + row) * H_DIM;
            #pragma unroll
            for (int nt = 0; nt < 4; ++nt) {
                int col = wn * 64 + nt * 16 + lr;
                float t = fmaf((acc[mt][nt][r] - mu) * inv, gv[nt], bev[nt]);
                op[col] = gelu_fast(t);
            }
        }
    }
}

extern "C" void kernel_launch(void* const* d_in, const int* in_sizes, int n_in,
                              void* d_out, int out_size, void* d_ws, size_t ws_size,
                              hipStream_t stream) {
    const float* x         = (const float*)d_in[0];
    const float* enc_w     = (const float*)d_in[1];
    const float* enc_b     = (const float*)d_in[2];
    const float* enc_gamma = (const float*)d_in[3];
    const float* enc_beta  = (const float*)d_in[4];
    const float* mod_w     = (const float*)d_in[5];
    const float* mod_b     = (const float*)d_in[6];
    const float* mod_gamma = (const float*)d_in[7];
    const float* mod_beta  = (const float*)d_in[8];
    float* out = (float*)d_out;

    const size_t wb_bytes = (size_t)H_DIM * K_DIM * sizeof(__bf16);   // 4 MB
    const size_t wf_off   = wb_bytes;
    const size_t bf_off   = wf_off + (size_t)C_CH * H_DIM * sizeof(float);  // +16 KB
    const size_t st_off   = bf_off + (size_t)C_CH * H_DIM * sizeof(float);  // +16 KB
    const size_t need     = st_off + (size_t)C_CH * 4 * sizeof(float);

    int use_ws = (ws_size >= need) ? 1 : 0;
    __bf16* Wb = (__bf16*)d_ws;
    float*  Wf = (float*)((char*)d_ws + wf_off);
    float*  Bf = (float*)((char*)d_ws + bf_off);
    float*  st = (float*)((char*)d_ws + st_off);

    static int attr_done = 0;
    if (!attr_done) {
        hipFuncSetAttribute((const void*)fused_gemm_kernel<1>,
                            hipFuncAttributeMaxDynamicSharedMemorySize, SM_SZ);
        hipFuncSetAttribute((const void*)fused_gemm_kernel<0>,
                            hipFuncAttributeMaxDynamicSharedMemorySize, SM_SZ);
        attr_done = 1;
    }

    if (use_ws) {
        prep_kernel<<<1024 + C_CH, 256, 0, stream>>>(
            mod_w, Wb, enc_w, enc_b, enc_gamma, Wf, Bf, st);
        fused_gemm_kernel<1><<<BS / TM, 512, SM_SZ, stream>>>(
            x, enc_w, enc_b, enc_gamma, enc_beta, mod_w, Wb, Wf, Bf, st,
            mod_b, mod_gamma, mod_beta, out);
    } else {
        fused_gemm_kernel<0><<<BS / TM, 512, SM_SZ, stream>>>(
            x, enc_w, enc_b, enc_gamma, enc_beta, mod_w, Wb,
            (const float*)0, (const float*)0, (const float*)0,
            mod_b, mod_gamma, mod_beta, out);
    }
}